// Round 3
// baseline (977.083 us; speedup 1.0000x reference)
//
#include <hip/hip_runtime.h>

typedef _Float16 f16;
typedef _Float16 f16x8 __attribute__((ext_vector_type(8)));
typedef __fp16   h16x2 __attribute__((ext_vector_type(2)));
typedef float    f32x4 __attribute__((ext_vector_type(4)));

constexpr int NB = 32, NN = 1024, KK = 1024, MO = 1024;
constexpr int BM = 128, BN = 128, BK = 32;
constexpr int LDA = 40;          // padded LDS row stride in f16 (80 B)
constexpr int NSTEP = KK / BK;   // 32

// Occupancy: LDS = 40960 B/block -> exactly 4 blocks/CU in 160 KiB.
// VGPR = 92 <= 128, so 16 waves/CU are legal. Previous (256,2) capped
// residency at 2 blocks/CU (21.6% occupancy measured) and left the
// per-K-step barrier drain (vmcnt(0) before s_barrier) exposed.
// (256,4) doubles the co-resident wave pool that hides that latency.
__global__ __launch_bounds__(256, 4)
void cond_linear_kernel(const float* __restrict__ x,
                        const int* __restrict__ task_id,
                        const float* __restrict__ W,
                        float* __restrict__ out) {
    __shared__ __align__(16) f16 As[2][BM * LDA];
    __shared__ __align__(16) f16 Bs[2][BN * LDA];

    const int bid   = blockIdx.x;
    const int batch = bid >> 6;
    const int tile  = bid & 63;
    // XCD swizzle: bid%8 == tile&7 == tm -> all 8 tn-tiles sharing an x-band
    // land on the same XCD's L2 (round-robin dispatch assumption; perf-only).
    const int tm = tile & 7;
    const int tn = tile >> 3;

    const int tid  = threadIdx.x;
    const int task = task_id[batch];

    const float* xb = x + (size_t)batch * NN * KK + (size_t)(tm * BM) * KK;
    const float* wb = W + (size_t)task * MO * KK + (size_t)(tn * BN) * KK;

    // staging: 512 chunks of 8 floats cover one 128x32 tile; each thread: 2 A + 2 B chunks
    const int c0 = tid, c1 = tid + 256;
    const int r0 = c0 >> 2, ko0 = (c0 & 3) * 8;
    const int r1 = c1 >> 2, ko1 = (c1 & 3) * 8;

    const float* pa0 = xb + r0 * KK + ko0;
    const float* pa1 = xb + r1 * KK + ko1;
    const float* pb0 = wb + r0 * KK + ko0;
    const float* pb1 = wb + r1 * KK + ko1;

    // two register tile-sets in flight (prefetch distance 2)
    f32x4 ra0[4], rb0[4], ra1[4], rb1[4];

    auto load0 = [&](int k0) {
        ra0[0] = *(const f32x4*)(pa0 + k0); ra0[1] = *(const f32x4*)(pa0 + k0 + 4);
        ra0[2] = *(const f32x4*)(pa1 + k0); ra0[3] = *(const f32x4*)(pa1 + k0 + 4);
        rb0[0] = *(const f32x4*)(pb0 + k0); rb0[1] = *(const f32x4*)(pb0 + k0 + 4);
        rb0[2] = *(const f32x4*)(pb1 + k0); rb0[3] = *(const f32x4*)(pb1 + k0 + 4);
    };
    auto load1 = [&](int k0) {
        ra1[0] = *(const f32x4*)(pa0 + k0); ra1[1] = *(const f32x4*)(pa0 + k0 + 4);
        ra1[2] = *(const f32x4*)(pa1 + k0); ra1[3] = *(const f32x4*)(pa1 + k0 + 4);
        rb1[0] = *(const f32x4*)(pb0 + k0); rb1[1] = *(const f32x4*)(pb0 + k0 + 4);
        rb1[2] = *(const f32x4*)(pb1 + k0); rb1[3] = *(const f32x4*)(pb1 + k0 + 4);
    };

    auto cvt8 = [](const f32x4& lo, const f32x4& hi) -> f16x8 {
        union { h16x2 h[4]; f16x8 v; } u;
        u.h[0] = __builtin_amdgcn_cvt_pkrtz(lo[0], lo[1]);
        u.h[1] = __builtin_amdgcn_cvt_pkrtz(lo[2], lo[3]);
        u.h[2] = __builtin_amdgcn_cvt_pkrtz(hi[0], hi[1]);
        u.h[3] = __builtin_amdgcn_cvt_pkrtz(hi[2], hi[3]);
        return u.v;
    };

    auto store0 = [&](int buf) {
        *(f16x8*)&As[buf][r0 * LDA + ko0] = cvt8(ra0[0], ra0[1]);
        *(f16x8*)&As[buf][r1 * LDA + ko1] = cvt8(ra0[2], ra0[3]);
        *(f16x8*)&Bs[buf][r0 * LDA + ko0] = cvt8(rb0[0], rb0[1]);
        *(f16x8*)&Bs[buf][r1 * LDA + ko1] = cvt8(rb0[2], rb0[3]);
    };
    auto store1 = [&](int buf) {
        *(f16x8*)&As[buf][r0 * LDA + ko0] = cvt8(ra1[0], ra1[1]);
        *(f16x8*)&As[buf][r1 * LDA + ko1] = cvt8(ra1[2], ra1[3]);
        *(f16x8*)&Bs[buf][r0 * LDA + ko0] = cvt8(rb1[0], rb1[1]);
        *(f16x8*)&Bs[buf][r1 * LDA + ko1] = cvt8(rb1[2], rb1[3]);
    };

    // wave layout: 2x2 waves, each 64x64 via 4x4 MFMA 16x16 tiles
    const int lane = tid & 63;
    const int wave = tid >> 6;
    const int wr   = (wave >> 1) * 64;
    const int wc   = (wave & 1) * 64;
    const int lm   = lane & 15;
    const int lq   = lane >> 4;

    f32x4 acc[4][4] = {};

    const int fa_off = (wr + lm) * LDA + lq * 8;
    const int fb_off = (wc + lm) * LDA + lq * 8;

    auto compute = [&](int buf) {
        f16x8 af[4], bf[4];
        #pragma unroll
        for (int i = 0; i < 4; ++i) af[i] = *(const f16x8*)&As[buf][fa_off + i * 16 * LDA];
        #pragma unroll
        for (int j = 0; j < 4; ++j) bf[j] = *(const f16x8*)&Bs[buf][fb_off + j * 16 * LDA];
        #pragma unroll
        for (int i = 0; i < 4; ++i)
            #pragma unroll
            for (int j = 0; j < 4; ++j)
                acc[i][j] = __builtin_amdgcn_mfma_f32_16x16x32_f16(af[i], bf[j], acc[i][j], 0, 0, 0);
    };

    // prologue: G(0), G(1) in flight; stage G(0) into LDS buf0
    load0(0);
    load1(BK);
    store0(0);
    __syncthreads();

    // steady state, manually unrolled x2 so register slots are compile-time.
    // iter ks: issue G(ks+2) into the slot freed last iter; compute buf ks&1;
    // stage G(ks+1) into buf (ks+1)&1; single barrier.
    for (int ks = 0; ks < NSTEP; ks += 2) {
        // even step: compute buf0, slot0 free -> load G(ks+2), store slot1 -> buf1
        if (ks + 2 < NSTEP) load0((ks + 2) * BK);
        compute(0);
        store1(1);
        __syncthreads();
        // odd step: compute buf1, slot1 free -> load G(ks+3), store slot0 -> buf0
        if (ks + 3 < NSTEP) load1((ks + 3) * BK);
        compute(1);
        if (ks + 2 < NSTEP) store0(0);
        __syncthreads();
    }

    // epilogue: C/D layout col=lane&15, row=(lane>>4)*4+reg  [m89-verified]
    float* ob = out + (size_t)batch * NN * MO + (size_t)(tm * BM) * MO + (tn * BN);
    #pragma unroll
    for (int i = 0; i < 4; ++i) {
        #pragma unroll
        for (int j = 0; j < 4; ++j) {
            const int row0 = wr + i * 16 + lq * 4;
            const int col  = wc + j * 16 + lm;
            #pragma unroll
            for (int r = 0; r < 4; ++r)
                ob[(size_t)(row0 + r) * MO + col] = acc[i][j][r];
        }
    }

    // second tuple output: task_id as float, at offset NB*NN*MO
    if (tile == 0 && tid == 0)
        out[(size_t)NB * NN * MO + batch] = (float)task;
}

extern "C" void kernel_launch(void* const* d_in, const int* in_sizes, int n_in,
                              void* d_out, int out_size, void* d_ws, size_t ws_size,
                              hipStream_t stream) {
    const float* x       = (const float*)d_in[0];
    const int*   task_id = (const int*)d_in[1];
    const float* W       = (const float*)d_in[2];
    float*       out     = (float*)d_out;

    dim3 grid(NB * (NN / BM) * (MO / BN));  // 2048
    dim3 block(256);
    cond_linear_kernel<<<grid, block, 0, stream>>>(x, task_id, W, out);
}

// Round 4
// 534.634 us; speedup vs baseline: 1.8276x; 1.8276x over previous
//
#include <hip/hip_runtime.h>

typedef _Float16 f16;
typedef _Float16 f16x8 __attribute__((ext_vector_type(8)));
typedef __fp16   h16x2 __attribute__((ext_vector_type(2)));
typedef float    f32x4 __attribute__((ext_vector_type(4)));

constexpr int NB = 32, NN = 1024, KK = 1024, MO = 1024;
constexpr int BM = 128, BN = 128, BK = 32;
constexpr int LDA = 40;          // padded LDS row stride in f16 (80 B)
constexpr int NSTEP = KK / BK;   // 32

// Occupancy history (measured):
//   (256,2): budget 256 regs/wave, uses 92 VGPR + 64 AGPR = 156 -> 2 blk/CU,
//            occupancy 21.6%, 196 us. Latency-bound, all pipes idle.
//   (256,4): budget 128 < 156 -> SPILL (VGPR forced to 64, WRITE_SIZE 131MB->1.84GB),
//            815 us. gfx950 unified VGPR/AGPR file: acc counts against budget!
//   (256,3): budget 170 >= 156 -> fits, 3 blk/CU = 12 waves/CU, LDS 120KiB <= 160KiB.
__global__ __launch_bounds__(256, 3)
void cond_linear_kernel(const float* __restrict__ x,
                        const int* __restrict__ task_id,
                        const float* __restrict__ W,
                        float* __restrict__ out) {
    __shared__ __align__(16) f16 As[2][BM * LDA];
    __shared__ __align__(16) f16 Bs[2][BN * LDA];

    const int bid   = blockIdx.x;
    const int batch = bid >> 6;
    const int tile  = bid & 63;
    // XCD swizzle: bid%8 == tile&7 == tm -> all 8 tn-tiles sharing an x-band
    // land on the same XCD's L2 (round-robin dispatch assumption; perf-only).
    const int tm = tile & 7;
    const int tn = tile >> 3;

    const int tid  = threadIdx.x;
    const int task = task_id[batch];

    const float* xb = x + (size_t)batch * NN * KK + (size_t)(tm * BM) * KK;
    const float* wb = W + (size_t)task * MO * KK + (size_t)(tn * BN) * KK;

    // staging: 512 chunks of 8 floats cover one 128x32 tile; each thread: 2 A + 2 B chunks
    const int c0 = tid, c1 = tid + 256;
    const int r0 = c0 >> 2, ko0 = (c0 & 3) * 8;
    const int r1 = c1 >> 2, ko1 = (c1 & 3) * 8;

    const float* pa0 = xb + r0 * KK + ko0;
    const float* pa1 = xb + r1 * KK + ko1;
    const float* pb0 = wb + r0 * KK + ko0;
    const float* pb1 = wb + r1 * KK + ko1;

    // two register tile-sets in flight (prefetch distance 2)
    f32x4 ra0[4], rb0[4], ra1[4], rb1[4];

    auto load0 = [&](int k0) {
        ra0[0] = *(const f32x4*)(pa0 + k0); ra0[1] = *(const f32x4*)(pa0 + k0 + 4);
        ra0[2] = *(const f32x4*)(pa1 + k0); ra0[3] = *(const f32x4*)(pa1 + k0 + 4);
        rb0[0] = *(const f32x4*)(pb0 + k0); rb0[1] = *(const f32x4*)(pb0 + k0 + 4);
        rb0[2] = *(const f32x4*)(pb1 + k0); rb0[3] = *(const f32x4*)(pb1 + k0 + 4);
    };
    auto load1 = [&](int k0) {
        ra1[0] = *(const f32x4*)(pa0 + k0); ra1[1] = *(const f32x4*)(pa0 + k0 + 4);
        ra1[2] = *(const f32x4*)(pa1 + k0); ra1[3] = *(const f32x4*)(pa1 + k0 + 4);
        rb1[0] = *(const f32x4*)(pb0 + k0); rb1[1] = *(const f32x4*)(pb0 + k0 + 4);
        rb1[2] = *(const f32x4*)(pb1 + k0); rb1[3] = *(const f32x4*)(pb1 + k0 + 4);
    };

    auto cvt8 = [](const f32x4& lo, const f32x4& hi) -> f16x8 {
        union { h16x2 h[4]; f16x8 v; } u;
        u.h[0] = __builtin_amdgcn_cvt_pkrtz(lo[0], lo[1]);
        u.h[1] = __builtin_amdgcn_cvt_pkrtz(lo[2], lo[3]);
        u.h[2] = __builtin_amdgcn_cvt_pkrtz(hi[0], hi[1]);
        u.h[3] = __builtin_amdgcn_cvt_pkrtz(hi[2], hi[3]);
        return u.v;
    };

    auto store0 = [&](int buf) {
        *(f16x8*)&As[buf][r0 * LDA + ko0] = cvt8(ra0[0], ra0[1]);
        *(f16x8*)&As[buf][r1 * LDA + ko1] = cvt8(ra0[2], ra0[3]);
        *(f16x8*)&Bs[buf][r0 * LDA + ko0] = cvt8(rb0[0], rb0[1]);
        *(f16x8*)&Bs[buf][r1 * LDA + ko1] = cvt8(rb0[2], rb0[3]);
    };
    auto store1 = [&](int buf) {
        *(f16x8*)&As[buf][r0 * LDA + ko0] = cvt8(ra1[0], ra1[1]);
        *(f16x8*)&As[buf][r1 * LDA + ko1] = cvt8(ra1[2], ra1[3]);
        *(f16x8*)&Bs[buf][r0 * LDA + ko0] = cvt8(rb1[0], rb1[1]);
        *(f16x8*)&Bs[buf][r1 * LDA + ko1] = cvt8(rb1[2], rb1[3]);
    };

    // wave layout: 2x2 waves, each 64x64 via 4x4 MFMA 16x16 tiles
    const int lane = tid & 63;
    const int wave = tid >> 6;
    const int wr   = (wave >> 1) * 64;
    const int wc   = (wave & 1) * 64;
    const int lm   = lane & 15;
    const int lq   = lane >> 4;

    f32x4 acc[4][4] = {};

    const int fa_off = (wr + lm) * LDA + lq * 8;
    const int fb_off = (wc + lm) * LDA + lq * 8;

    auto compute = [&](int buf) {
        f16x8 af[4], bf[4];
        #pragma unroll
        for (int i = 0; i < 4; ++i) af[i] = *(const f16x8*)&As[buf][fa_off + i * 16 * LDA];
        #pragma unroll
        for (int j = 0; j < 4; ++j) bf[j] = *(const f16x8*)&Bs[buf][fb_off + j * 16 * LDA];
        #pragma unroll
        for (int i = 0; i < 4; ++i)
            #pragma unroll
            for (int j = 0; j < 4; ++j)
                acc[i][j] = __builtin_amdgcn_mfma_f32_16x16x32_f16(af[i], bf[j], acc[i][j], 0, 0, 0);
    };

    // prologue: G(0), G(1) in flight; stage G(0) into LDS buf0
    load0(0);
    load1(BK);
    store0(0);
    __syncthreads();

    // steady state, manually unrolled x2 so register slots are compile-time.
    // iter ks: issue G(ks+2) into the slot freed last iter; compute buf ks&1;
    // stage G(ks+1) into buf (ks+1)&1; single barrier.
    for (int ks = 0; ks < NSTEP; ks += 2) {
        // even step: compute buf0, slot0 free -> load G(ks+2), store slot1 -> buf1
        if (ks + 2 < NSTEP) load0((ks + 2) * BK);
        compute(0);
        store1(1);
        __syncthreads();
        // odd step: compute buf1, slot1 free -> load G(ks+3), store slot0 -> buf0
        if (ks + 3 < NSTEP) load1((ks + 3) * BK);
        compute(1);
        if (ks + 2 < NSTEP) store0(0);
        __syncthreads();
    }

    // epilogue: C/D layout col=lane&15, row=(lane>>4)*4+reg  [m89-verified]
    float* ob = out + (size_t)batch * NN * MO + (size_t)(tm * BM) * MO + (tn * BN);
    #pragma unroll
    for (int i = 0; i < 4; ++i) {
        #pragma unroll
        for (int j = 0; j < 4; ++j) {
            const int row0 = wr + i * 16 + lq * 4;
            const int col  = wc + j * 16 + lm;
            #pragma unroll
            for (int r = 0; r < 4; ++r)
                ob[(size_t)(row0 + r) * MO + col] = acc[i][j][r];
        }
    }

    // second tuple output: task_id as float, at offset NB*NN*MO
    if (tile == 0 && tid == 0)
        out[(size_t)NB * NN * MO + batch] = (float)task;
}

extern "C" void kernel_launch(void* const* d_in, const int* in_sizes, int n_in,
                              void* d_out, int out_size, void* d_ws, size_t ws_size,
                              hipStream_t stream) {
    const float* x       = (const float*)d_in[0];
    const int*   task_id = (const int*)d_in[1];
    const float* W       = (const float*)d_in[2];
    float*       out     = (float*)d_out;

    dim3 grid(NB * (NN / BM) * (MO / BN));  // 2048
    dim3 block(256);
    cond_linear_kernel<<<grid, block, 0, stream>>>(x, task_id, W, out);
}

// Round 5
// 371.642 us; speedup vs baseline: 2.6291x; 1.4386x over previous
//
#include <hip/hip_runtime.h>

typedef _Float16 f16;
typedef _Float16 f16x8 __attribute__((ext_vector_type(8)));
typedef __fp16   h16x2 __attribute__((ext_vector_type(2)));
typedef float    f32x4 __attribute__((ext_vector_type(4)));

constexpr int NB = 32, NN = 1024, KK = 1024, MO = 1024;
constexpr int BM = 128, BN = 128, BK = 32;
constexpr int LDA = 40;          // padded LDS row stride in f16 (80 B)
constexpr int NSTEP = KK / BK;   // 32

// Occupancy ladder (measured): (256,2)=196us no-spill; (256,3)=362us spills
// ~485MB; (256,4)=815us spills ~1.7GB. gfx950 unified VGPR/AGPR file: the
// acc[4][4] f32x4 counts against the per-wave budget, so 2 blocks/CU is the
// cap at this tile shape. Keep (256,2); attack the barrier drain instead.
__global__ __launch_bounds__(256, 2)
void cond_linear_kernel(const float* __restrict__ x,
                        const int* __restrict__ task_id,
                        const float* __restrict__ W,
                        float* __restrict__ out) {
    __shared__ __align__(16) f16 As[2][BM * LDA];
    __shared__ __align__(16) f16 Bs[2][BN * LDA];

    const int bid   = blockIdx.x;
    const int batch = bid >> 6;
    const int tile  = bid & 63;
    // XCD swizzle: bid%8 == tile&7 == tm -> all 8 tn-tiles sharing an x-band
    // land on the same XCD's L2 (round-robin dispatch assumption; perf-only).
    const int tm = tile & 7;
    const int tn = tile >> 3;

    const int tid  = threadIdx.x;
    const int task = task_id[batch];

    const float* xb = x + (size_t)batch * NN * KK + (size_t)(tm * BM) * KK;
    const float* wb = W + (size_t)task * MO * KK + (size_t)(tn * BN) * KK;

    // staging: 512 chunks of 8 floats cover one 128x32 tile; each thread: 2 A + 2 B chunks
    const int c0 = tid, c1 = tid + 256;
    const int r0 = c0 >> 2, ko0 = (c0 & 3) * 8;
    const int r1 = c1 >> 2, ko1 = (c1 & 3) * 8;

    const float* pa0 = xb + r0 * KK + ko0;
    const float* pa1 = xb + r1 * KK + ko1;
    const float* pb0 = wb + r0 * KK + ko0;
    const float* pb1 = wb + r1 * KK + ko1;

    // two register tile-sets in flight (prefetch distance 2)
    f32x4 ra0[4], rb0[4], ra1[4], rb1[4];

    auto load0 = [&](int k0) {
        ra0[0] = *(const f32x4*)(pa0 + k0); ra0[1] = *(const f32x4*)(pa0 + k0 + 4);
        ra0[2] = *(const f32x4*)(pa1 + k0); ra0[3] = *(const f32x4*)(pa1 + k0 + 4);
        rb0[0] = *(const f32x4*)(pb0 + k0); rb0[1] = *(const f32x4*)(pb0 + k0 + 4);
        rb0[2] = *(const f32x4*)(pb1 + k0); rb0[3] = *(const f32x4*)(pb1 + k0 + 4);
    };
    auto load1 = [&](int k0) {
        ra1[0] = *(const f32x4*)(pa0 + k0); ra1[1] = *(const f32x4*)(pa0 + k0 + 4);
        ra1[2] = *(const f32x4*)(pa1 + k0); ra1[3] = *(const f32x4*)(pa1 + k0 + 4);
        rb1[0] = *(const f32x4*)(pb0 + k0); rb1[1] = *(const f32x4*)(pb0 + k0 + 4);
        rb1[2] = *(const f32x4*)(pb1 + k0); rb1[3] = *(const f32x4*)(pb1 + k0 + 4);
    };

    auto cvt8 = [](const f32x4& lo, const f32x4& hi) -> f16x8 {
        union { h16x2 h[4]; f16x8 v; } u;
        u.h[0] = __builtin_amdgcn_cvt_pkrtz(lo[0], lo[1]);
        u.h[1] = __builtin_amdgcn_cvt_pkrtz(lo[2], lo[3]);
        u.h[2] = __builtin_amdgcn_cvt_pkrtz(hi[0], hi[1]);
        u.h[3] = __builtin_amdgcn_cvt_pkrtz(hi[2], hi[3]);
        return u.v;
    };

    auto store0 = [&](int buf) {
        *(f16x8*)&As[buf][r0 * LDA + ko0] = cvt8(ra0[0], ra0[1]);
        *(f16x8*)&As[buf][r1 * LDA + ko1] = cvt8(ra0[2], ra0[3]);
        *(f16x8*)&Bs[buf][r0 * LDA + ko0] = cvt8(rb0[0], rb0[1]);
        *(f16x8*)&Bs[buf][r1 * LDA + ko1] = cvt8(rb0[2], rb0[3]);
    };
    auto store1 = [&](int buf) {
        *(f16x8*)&As[buf][r0 * LDA + ko0] = cvt8(ra1[0], ra1[1]);
        *(f16x8*)&As[buf][r1 * LDA + ko1] = cvt8(ra1[2], ra1[3]);
        *(f16x8*)&Bs[buf][r0 * LDA + ko0] = cvt8(rb1[0], rb1[1]);
        *(f16x8*)&Bs[buf][r1 * LDA + ko1] = cvt8(rb1[2], rb1[3]);
    };

    // LDS-only barrier: staging is register-staged, so in-flight global loads
    // (private reg destinations) may legally cross the barrier. Only LDS ops
    // must drain (my ds_writes visible; my ds_reads done before buffer reuse).
    // __syncthreads() would emit s_waitcnt vmcnt(0) and collapse the prefetch
    // distance to 0 — this is the m97-structure ~20% barrier-drain stall.
    // Register-dependency vmcnt(N) before each load's first use is inserted by
    // the compiler and preserves correctness.
    auto lds_barrier = [] {
        asm volatile("s_waitcnt lgkmcnt(0)" ::: "memory");
        __builtin_amdgcn_s_barrier();
    };

    // wave layout: 2x2 waves, each 64x64 via 4x4 MFMA 16x16 tiles
    const int lane = tid & 63;
    const int wave = tid >> 6;
    const int wr   = (wave >> 1) * 64;
    const int wc   = (wave & 1) * 64;
    const int lm   = lane & 15;
    const int lq   = lane >> 4;

    f32x4 acc[4][4] = {};

    const int fa_off = (wr + lm) * LDA + lq * 8;
    const int fb_off = (wc + lm) * LDA + lq * 8;

    auto compute = [&](int buf) {
        f16x8 af[4], bf[4];
        #pragma unroll
        for (int i = 0; i < 4; ++i) af[i] = *(const f16x8*)&As[buf][fa_off + i * 16 * LDA];
        #pragma unroll
        for (int j = 0; j < 4; ++j) bf[j] = *(const f16x8*)&Bs[buf][fb_off + j * 16 * LDA];
        #pragma unroll
        for (int i = 0; i < 4; ++i)
            #pragma unroll
            for (int j = 0; j < 4; ++j)
                acc[i][j] = __builtin_amdgcn_mfma_f32_16x16x32_f16(af[i], bf[j], acc[i][j], 0, 0, 0);
    };

    // prologue: G(0), G(1) in flight; stage G(0) into LDS buf0
    load0(0);
    load1(BK);
    store0(0);
    lds_barrier();

    // steady state, manually unrolled x2 so register slots are compile-time.
    // iter ks: issue G(ks+2) into the slot freed last iter; compute buf ks&1;
    // stage G(ks+1) into buf (ks+1)&1; single barrier.
    for (int ks = 0; ks < NSTEP; ks += 2) {
        // even step: compute buf0, slot0 free -> load G(ks+2), store slot1 -> buf1
        if (ks + 2 < NSTEP) load0((ks + 2) * BK);
        compute(0);
        store1(1);
        lds_barrier();
        // odd step: compute buf1, slot1 free -> load G(ks+3), store slot0 -> buf0
        if (ks + 3 < NSTEP) load1((ks + 3) * BK);
        compute(1);
        if (ks + 2 < NSTEP) store0(0);
        lds_barrier();
    }

    // epilogue: C/D layout col=lane&15, row=(lane>>4)*4+reg  [m89-verified]
    float* ob = out + (size_t)batch * NN * MO + (size_t)(tm * BM) * MO + (tn * BN);
    #pragma unroll
    for (int i = 0; i < 4; ++i) {
        #pragma unroll
        for (int j = 0; j < 4; ++j) {
            const int row0 = wr + i * 16 + lq * 4;
            const int col  = wc + j * 16 + lm;
            #pragma unroll
            for (int r = 0; r < 4; ++r)
                ob[(size_t)(row0 + r) * MO + col] = acc[i][j][r];
        }
    }

    // second tuple output: task_id as float, at offset NB*NN*MO
    if (tile == 0 && tid == 0)
        out[(size_t)NB * NN * MO + batch] = (float)task;
}

extern "C" void kernel_launch(void* const* d_in, const int* in_sizes, int n_in,
                              void* d_out, int out_size, void* d_ws, size_t ws_size,
                              hipStream_t stream) {
    const float* x       = (const float*)d_in[0];
    const int*   task_id = (const int*)d_in[1];
    const float* W       = (const float*)d_in[2];
    float*       out     = (float*)d_out;

    dim3 grid(NB * (NN / BM) * (MO / BN));  // 2048
    dim3 block(256);
    cond_linear_kernel<<<grid, block, 0, stream>>>(x, task_id, W, out);
}